// Round 1
// baseline (972.243 us; speedup 1.0000x reference)
//
#include <hip/hip_runtime.h>

#define N_NODES 50000
#define N_EDGES 800000
#define N_GRAPHS 1024
#define D_IN 64
#define D_PROT 1280
#define HID 256

#define NPB 64   // nodes per block in k_node
#define GPB 4    // graphs per block in k_graph

// ---------------------------------------------------------------------------
// K1: edge scatter — aggr[dst] += x[src], deg[dst] += 1
// 16 lanes per edge, float4 gather, scalar fp32 atomics (51.2M total).
// ---------------------------------------------------------------------------
__global__ __launch_bounds__(256) void k_edge(
    const float* __restrict__ x, const int* __restrict__ ei,
    float* __restrict__ aggr, float* __restrict__ deg) {
  int idx = blockIdx.x * 256 + threadIdx.x;
  int e  = idx >> 4;           // edge id (16 lanes per edge)
  int l4 = (idx & 15) * 4;     // feature offset (float4 granule)
  if (e >= N_EDGES) return;
  int src = ei[e];
  int dst = ei[N_EDGES + e];
  const float4 v = *(const float4*)(x + src * D_IN + l4);
  float* a = aggr + dst * D_IN + l4;
  atomicAdd(a + 0, v.x);
  atomicAdd(a + 1, v.y);
  atomicAdd(a + 2, v.z);
  atomicAdd(a + 3, v.w);
  if ((idx & 15) == 0) atomicAdd(&deg[dst], 1.0f);
}

// ---------------------------------------------------------------------------
// K2: per-node MLP + graph mean-pool accumulate.
//   drug = relu(bl + (aggr/deg) @ Wl + x @ Wr); pooled_sum[batch[n]] += drug
// Thread t owns output column t; weight columns Wl[:,t], Wr[:,t] live in
// registers (128 VGPRs). 64-node row chunks staged in LDS, read as float4.
// batch is sorted -> run-length local accumulation, few atomics.
// ---------------------------------------------------------------------------
__global__ __launch_bounds__(256, 2) void k_node(
    const float* __restrict__ x, const float* __restrict__ aggr,
    const float* __restrict__ deg,
    const float* __restrict__ Wl, const float* __restrict__ bl,
    const float* __restrict__ Wr, const int* __restrict__ batch,
    float* __restrict__ pooled, float* __restrict__ gcnt) {
  __shared__ float sA[NPB * D_IN];   // 16 KB
  __shared__ float sX[NPB * D_IN];   // 16 KB
  __shared__ float sScale[NPB];
  __shared__ int   sG[NPB];

  const int t  = threadIdx.x;
  const int n0 = blockIdx.x * NPB;
  const int nn = min(NPB, N_NODES - n0);

  // register-resident weight columns
  float wl[D_IN], wr[D_IN];
#pragma unroll
  for (int k = 0; k < D_IN; ++k) {
    wl[k] = Wl[k * HID + t];
    wr[k] = Wr[k * HID + t];
  }
  const float bias = bl[t];

  // stage node rows (contiguous region: nodes n0..n0+nn-1)
  for (int i = t; i < nn * D_IN; i += 256) {
    sA[i] = aggr[n0 * D_IN + i];
    sX[i] = x[n0 * D_IN + i];
  }
  for (int i = t; i < nn; i += 256) {
    sScale[i] = 1.0f / fmaxf(deg[n0 + i], 1.0f);
    sG[i] = batch[n0 + i];
  }
  __syncthreads();

  float lacc = 0.0f;
  int curg = sG[0];
  int runstart = 0;
  for (int n = 0; n < nn; ++n) {
    int g = sG[n];
    if (g != curg) {
      atomicAdd(&pooled[curg * HID + t], lacc);
      if (t == 0) atomicAdd(&gcnt[curg], (float)(n - runstart));
      lacc = 0.0f; curg = g; runstart = n;
    }
    const float4* a4 = (const float4*)(sA + n * D_IN);
    const float4* x4 = (const float4*)(sX + n * D_IN);
    float d1 = 0.0f, d2 = 0.0f;
#pragma unroll
    for (int k = 0; k < D_IN / 4; ++k) {
      float4 a = a4[k];
      float4 xx = x4[k];
      d1 = fmaf(a.x,  wl[4 * k + 0], d1);
      d1 = fmaf(a.y,  wl[4 * k + 1], d1);
      d1 = fmaf(a.z,  wl[4 * k + 2], d1);
      d1 = fmaf(a.w,  wl[4 * k + 3], d1);
      d2 = fmaf(xx.x, wr[4 * k + 0], d2);
      d2 = fmaf(xx.y, wr[4 * k + 1], d2);
      d2 = fmaf(xx.z, wr[4 * k + 2], d2);
      d2 = fmaf(xx.w, wr[4 * k + 3], d2);
    }
    float v = bias + sScale[n] * d1 + d2;
    lacc += fmaxf(v, 0.0f);
  }
  atomicAdd(&pooled[curg * HID + t], lacc);
  if (t == 0) atomicAdd(&gcnt[curg], (float)(nn - runstart));
}

// ---------------------------------------------------------------------------
// K3: per-graph tail.
//   protein = pe @ Wp + bp ; combined = [pooled_sum/cnt | protein]
//   inter = relu(combined @ Wi + bi) ; out = inter @ Wo + bo
// GPB graphs per block; thread t owns column t; pe rows staged in LDS.
// ---------------------------------------------------------------------------
__global__ __launch_bounds__(256) void k_graph(
    const float* __restrict__ pe,
    const float* __restrict__ Wp, const float* __restrict__ bp,
    const float* __restrict__ pooled, const float* __restrict__ gcnt,
    const float* __restrict__ Wi, const float* __restrict__ bi,
    const float* __restrict__ Wo, const float* __restrict__ bo,
    float* __restrict__ out) {
  __shared__ float sPE[GPB * D_PROT];      // 20 KB
  __shared__ float sComb[GPB * 2 * HID];   // 8 KB
  __shared__ float sRed[256];

  const int t  = threadIdx.x;
  const int g0 = blockIdx.x * GPB;

  for (int i = t; i < GPB * D_PROT; i += 256) sPE[i] = pe[g0 * D_PROT + i];
  __syncthreads();

  // protein_x columns
  float accp[GPB];
#pragma unroll
  for (int g = 0; g < GPB; ++g) accp[g] = 0.0f;
  for (int k = 0; k < D_PROT; ++k) {
    float w = Wp[k * HID + t];
#pragma unroll
    for (int g = 0; g < GPB; ++g) accp[g] = fmaf(sPE[g * D_PROT + k], w, accp[g]);
  }
  const float bpt = bp[t];
#pragma unroll
  for (int g = 0; g < GPB; ++g) {
    float inv = 1.0f / fmaxf(gcnt[g0 + g], 1.0f);
    sComb[g * 2 * HID + t]       = pooled[(g0 + g) * HID + t] * inv;
    sComb[g * 2 * HID + HID + t] = accp[g] + bpt;
  }
  __syncthreads();

  // interaction columns
  float acci[GPB];
  const float bit = bi[t];
#pragma unroll
  for (int g = 0; g < GPB; ++g) acci[g] = bit;
  for (int j = 0; j < 2 * HID; ++j) {
    float w = Wi[j * HID + t];
#pragma unroll
    for (int g = 0; g < GPB; ++g) acci[g] = fmaf(sComb[g * 2 * HID + j], w, acci[g]);
  }

  // head: out[g] = sum_t relu(acci[g]) * Wo[t] + bo
  const float wo = Wo[t];
  for (int g = 0; g < GPB; ++g) {
    float p = fmaxf(acci[g], 0.0f) * wo;
    sRed[t] = p;
    __syncthreads();
    for (int s2 = 128; s2 > 0; s2 >>= 1) {
      if (t < s2) sRed[t] += sRed[t + s2];
      __syncthreads();
    }
    if (t == 0) out[g0 + g] = sRed[0] + bo[0];
    __syncthreads();
  }
}

extern "C" void kernel_launch(void* const* d_in, const int* in_sizes, int n_in,
                              void* d_out, int out_size, void* d_ws, size_t ws_size,
                              hipStream_t stream) {
  const float* x     = (const float*)d_in[0];
  const float* pe    = (const float*)d_in[1];
  const float* Wl    = (const float*)d_in[2];
  const float* bl    = (const float*)d_in[3];
  const float* Wr    = (const float*)d_in[4];
  const float* Wp    = (const float*)d_in[5];
  const float* bp    = (const float*)d_in[6];
  const float* Wi    = (const float*)d_in[7];
  const float* bi    = (const float*)d_in[8];
  const float* Wo    = (const float*)d_in[9];
  const float* bo    = (const float*)d_in[10];
  const int*   ei    = (const int*)d_in[11];
  const int*   batch = (const int*)d_in[12];
  float* out = (float*)d_out;

  // workspace layout (floats)
  float* aggr   = (float*)d_ws;                 // N_NODES * D_IN
  float* deg    = aggr + N_NODES * D_IN;        // N_NODES
  float* pooled = deg + N_NODES;                // N_GRAPHS * HID
  float* gcnt   = pooled + N_GRAPHS * HID;      // N_GRAPHS

  size_t zbytes = (size_t)(N_NODES * D_IN + N_NODES + N_GRAPHS * HID + N_GRAPHS)
                  * sizeof(float);
  hipMemsetAsync(d_ws, 0, zbytes, stream);

  int edge_threads = N_EDGES * 16;
  k_edge<<<(edge_threads + 255) / 256, 256, 0, stream>>>(x, ei, aggr, deg);
  k_node<<<(N_NODES + NPB - 1) / NPB, 256, 0, stream>>>(
      x, aggr, deg, Wl, bl, Wr, batch, pooled, gcnt);
  k_graph<<<N_GRAPHS / GPB, 256, 0, stream>>>(
      pe, Wp, bp, pooled, gcnt, Wi, bi, Wo, bo, out);
}

// Round 2
// 456.352 us; speedup vs baseline: 2.1305x; 2.1305x over previous
//
#include <hip/hip_runtime.h>

#define N_NODES 50000
#define N_EDGES 800000
#define N_GRAPHS 1024
#define D_IN 64
#define D_PROT 1280
#define HID 256

#define NPB 64   // nodes per block in k_node
#define GPB 4    // graphs per block in k_graph

// ---------------------------------------------------------------------------
// CSR build stage 1: in-degree histogram (int atomics — 800K, ~11 µs)
// ---------------------------------------------------------------------------
__global__ __launch_bounds__(256) void k_hist(const int* __restrict__ ei,
                                              int* __restrict__ degi) {
  int e = blockIdx.x * 256 + threadIdx.x;
  if (e < N_EDGES) atomicAdd(&degi[ei[N_EDGES + e]], 1);
}

// ---------------------------------------------------------------------------
// CSR build stage 2: exclusive prefix sum over deg -> rowptr[0..N_NODES]
// Single block, 1024 threads, wave-shuffle scan + serial wave-sum combine.
// ---------------------------------------------------------------------------
__global__ __launch_bounds__(1024) void k_scan(const int* __restrict__ degi,
                                               int* __restrict__ rowptr) {
  __shared__ int wsum[16];
  __shared__ int s_carry;
  const int t = threadIdx.x, lane = t & 63, wave = t >> 6;
  if (t == 0) { s_carry = 0; rowptr[0] = 0; }
  for (int base = 0; base < N_NODES; base += 1024) {
    __syncthreads();  // protect wsum/s_carry from previous iteration's readers
    int i = base + t;
    int v = (i < N_NODES) ? degi[i] : 0;
    int sc = v;  // inclusive scan within wave
#pragma unroll
    for (int off = 1; off < 64; off <<= 1) {
      int u = __shfl_up(sc, off);
      if (lane >= off) sc += u;
    }
    if (lane == 63) wsum[wave] = sc;
    __syncthreads();
    if (t == 0) {  // turn wave totals into exclusive offsets incl. carry
      int run = s_carry;
      for (int w = 0; w < 16; ++w) { int vv = wsum[w]; wsum[w] = run; run += vv; }
      s_carry = run;
    }
    __syncthreads();
    if (i < N_NODES) rowptr[i + 1] = wsum[wave] + sc;
  }
}

// ---------------------------------------------------------------------------
// CSR build stage 3: bucket-fill edge sources by dst.
// ---------------------------------------------------------------------------
__global__ __launch_bounds__(256) void k_fill(const int* __restrict__ ei,
                                              const int* __restrict__ rowptr,
                                              int* __restrict__ cursor,
                                              int* __restrict__ esrc) {
  int e = blockIdx.x * 256 + threadIdx.x;
  if (e >= N_EDGES) return;
  int dst = ei[N_EDGES + e];
  int pos = atomicAdd(&cursor[dst], 1);
  esrc[rowptr[dst] + pos] = ei[e];
}

// ---------------------------------------------------------------------------
// K2: fused neighbor-gather + per-node MLP + graph mean-pool accumulate.
//   aggr_n = mean_{s in N(n)} x[s]          (CSR gather, no float atomics)
//   drug   = relu(bl + aggr_n @ Wl + x_n @ Wr)
//   pooled_sum[batch[n]] += drug            (run-length, few atomics)
// 4 wave-groups of 64 lanes; group w aggregates nodes n0+w, n0+w+4, ...
// lane f owns feature f -> 256B coalesced read per neighbor row.
// ---------------------------------------------------------------------------
__global__ __launch_bounds__(256, 2) void k_node(
    const float* __restrict__ x, const int* __restrict__ rowptr,
    const int* __restrict__ esrc,
    const float* __restrict__ Wl, const float* __restrict__ bl,
    const float* __restrict__ Wr, const int* __restrict__ batch,
    float* __restrict__ pooled, float* __restrict__ gcnt) {
  __shared__ float sA[NPB * D_IN];   // 16 KB aggregated (mean) rows
  __shared__ float sX[NPB * D_IN];   // 16 KB self rows
  __shared__ int   sG[NPB];

  const int t  = threadIdx.x;
  const int n0 = blockIdx.x * NPB;
  const int nn = min(NPB, N_NODES - n0);

  // register-resident weight columns (thread t owns output column t)
  float wl[D_IN], wr[D_IN];
#pragma unroll
  for (int k = 0; k < D_IN; ++k) {
    wl[k] = Wl[k * HID + t];
    wr[k] = Wr[k * HID + t];
  }
  const float bias = bl[t];

  // stage self rows (contiguous) + batch ids
  for (int i = t; i < nn * D_IN; i += 256) sX[i] = x[n0 * D_IN + i];
  for (int i = t; i < nn; i += 256) sG[i] = batch[n0 + i];

  // neighbor gather: wave w handles nodes w, w+4, ... ; lane f = feature f
  const int w = t >> 6, f = t & 63;
  for (int n = w; n < nn; n += 4) {
    const int node = n0 + n;
    const int beg = rowptr[node], end = rowptr[node + 1];
    float a0 = 0.f, a1 = 0.f, a2 = 0.f, a3 = 0.f;
    int e = beg;
    for (; e + 4 <= end; e += 4) {  // 4 independent loads in flight
      int s0 = esrc[e], s1 = esrc[e + 1], s2 = esrc[e + 2], s3 = esrc[e + 3];
      a0 += x[s0 * D_IN + f];
      a1 += x[s1 * D_IN + f];
      a2 += x[s2 * D_IN + f];
      a3 += x[s3 * D_IN + f];
    }
    for (; e < end; ++e) a0 += x[esrc[e] * D_IN + f];
    float sum = (a0 + a1) + (a2 + a3);
    sA[n * D_IN + f] = sum * (1.0f / (float)max(end - beg, 1));
  }
  __syncthreads();

  // MLP + sorted-batch run-length pool accumulation
  float lacc = 0.0f;
  int curg = sG[0];
  int runstart = 0;
  for (int n = 0; n < nn; ++n) {
    int g = sG[n];
    if (g != curg) {
      atomicAdd(&pooled[curg * HID + t], lacc);
      if (t == 0) atomicAdd(&gcnt[curg], (float)(n - runstart));
      lacc = 0.0f; curg = g; runstart = n;
    }
    const float4* a4 = (const float4*)(sA + n * D_IN);
    const float4* x4 = (const float4*)(sX + n * D_IN);
    float d1 = 0.0f, d2 = 0.0f;
#pragma unroll
    for (int k = 0; k < D_IN / 4; ++k) {
      float4 a = a4[k];
      float4 xx = x4[k];
      d1 = fmaf(a.x,  wl[4 * k + 0], d1);
      d1 = fmaf(a.y,  wl[4 * k + 1], d1);
      d1 = fmaf(a.z,  wl[4 * k + 2], d1);
      d1 = fmaf(a.w,  wl[4 * k + 3], d1);
      d2 = fmaf(xx.x, wr[4 * k + 0], d2);
      d2 = fmaf(xx.y, wr[4 * k + 1], d2);
      d2 = fmaf(xx.z, wr[4 * k + 2], d2);
      d2 = fmaf(xx.w, wr[4 * k + 3], d2);
    }
    float v = bias + d1 + d2;
    lacc += fmaxf(v, 0.0f);
  }
  atomicAdd(&pooled[curg * HID + t], lacc);
  if (t == 0) atomicAdd(&gcnt[curg], (float)(nn - runstart));
}

// ---------------------------------------------------------------------------
// K3: per-graph tail (unchanged this round).
// ---------------------------------------------------------------------------
__global__ __launch_bounds__(256) void k_graph(
    const float* __restrict__ pe,
    const float* __restrict__ Wp, const float* __restrict__ bp,
    const float* __restrict__ pooled, const float* __restrict__ gcnt,
    const float* __restrict__ Wi, const float* __restrict__ bi,
    const float* __restrict__ Wo, const float* __restrict__ bo,
    float* __restrict__ out) {
  __shared__ float sPE[GPB * D_PROT];      // 20 KB
  __shared__ float sComb[GPB * 2 * HID];   // 8 KB
  __shared__ float sRed[256];

  const int t  = threadIdx.x;
  const int g0 = blockIdx.x * GPB;

  for (int i = t; i < GPB * D_PROT; i += 256) sPE[i] = pe[g0 * D_PROT + i];
  __syncthreads();

  float accp[GPB];
#pragma unroll
  for (int g = 0; g < GPB; ++g) accp[g] = 0.0f;
  for (int k = 0; k < D_PROT; ++k) {
    float wv = Wp[k * HID + t];
#pragma unroll
    for (int g = 0; g < GPB; ++g) accp[g] = fmaf(sPE[g * D_PROT + k], wv, accp[g]);
  }
  const float bpt = bp[t];
#pragma unroll
  for (int g = 0; g < GPB; ++g) {
    float inv = 1.0f / fmaxf(gcnt[g0 + g], 1.0f);
    sComb[g * 2 * HID + t]       = pooled[(g0 + g) * HID + t] * inv;
    sComb[g * 2 * HID + HID + t] = accp[g] + bpt;
  }
  __syncthreads();

  float acci[GPB];
  const float bit = bi[t];
#pragma unroll
  for (int g = 0; g < GPB; ++g) acci[g] = bit;
  for (int j = 0; j < 2 * HID; ++j) {
    float wv = Wi[j * HID + t];
#pragma unroll
    for (int g = 0; g < GPB; ++g) acci[g] = fmaf(sComb[g * 2 * HID + j], wv, acci[g]);
  }

  const float wo = Wo[t];
  for (int g = 0; g < GPB; ++g) {
    float p = fmaxf(acci[g], 0.0f) * wo;
    sRed[t] = p;
    __syncthreads();
    for (int s2 = 128; s2 > 0; s2 >>= 1) {
      if (t < s2) sRed[t] += sRed[t + s2];
      __syncthreads();
    }
    if (t == 0) out[g0 + g] = sRed[0] + bo[0];
    __syncthreads();
  }
}

extern "C" void kernel_launch(void* const* d_in, const int* in_sizes, int n_in,
                              void* d_out, int out_size, void* d_ws, size_t ws_size,
                              hipStream_t stream) {
  const float* x     = (const float*)d_in[0];
  const float* pe    = (const float*)d_in[1];
  const float* Wl    = (const float*)d_in[2];
  const float* bl    = (const float*)d_in[3];
  const float* Wr    = (const float*)d_in[4];
  const float* Wp    = (const float*)d_in[5];
  const float* bp    = (const float*)d_in[6];
  const float* Wi    = (const float*)d_in[7];
  const float* bi    = (const float*)d_in[8];
  const float* Wo    = (const float*)d_in[9];
  const float* bo    = (const float*)d_in[10];
  const int*   ei    = (const int*)d_in[11];
  const int*   batch = (const int*)d_in[12];
  float* out = (float*)d_out;

  // workspace layout — zeroed region first (single memset)
  int*   degi   = (int*)d_ws;                          // N_NODES
  int*   cursor = degi + N_NODES;                      // N_NODES
  float* pooled = (float*)(cursor + N_NODES);          // N_GRAPHS*HID
  float* gcnt   = pooled + N_GRAPHS * HID;             // N_GRAPHS
  int*   rowptr = (int*)(gcnt + N_GRAPHS);             // N_NODES+1 (fully written)
  int*   esrc   = rowptr + (N_NODES + 1);              // N_EDGES   (fully written)

  size_t zbytes = (size_t)(2 * N_NODES + N_GRAPHS * HID + N_GRAPHS) * sizeof(float);
  hipMemsetAsync(d_ws, 0, zbytes, stream);

  k_hist<<<(N_EDGES + 255) / 256, 256, 0, stream>>>(ei, degi);
  k_scan<<<1, 1024, 0, stream>>>(degi, rowptr);
  k_fill<<<(N_EDGES + 255) / 256, 256, 0, stream>>>(ei, rowptr, cursor, esrc);
  k_node<<<(N_NODES + NPB - 1) / NPB, 256, 0, stream>>>(
      x, rowptr, esrc, Wl, bl, Wr, batch, pooled, gcnt);
  k_graph<<<N_GRAPHS / GPB, 256, 0, stream>>>(
      pe, Wp, bp, pooled, gcnt, Wi, bi, Wo, bo, out);
}

// Round 3
// 326.196 us; speedup vs baseline: 2.9805x; 1.3990x over previous
//
#include <hip/hip_runtime.h>
#include <hip/hip_bf16.h>

#define N_NODES 50000
#define N_EDGES 800000
#define N_GRAPHS 1024
#define D_IN 64
#define D_PROT 1280
#define HID 256
#define GPB 4

#define N_PAD 50048  // N_NODES padded to multiple of 64

typedef __attribute__((ext_vector_type(8))) short short8;
typedef __attribute__((ext_vector_type(4))) float f32x4;
typedef __hip_bfloat16 bf16;

// ---------------------------------------------------------------------------
// k_prep: one launch doing all conversions/packing + per-graph node counts.
// Regions by blockIdx: x->bf16, pe->bf16, gcnt histogram, pack Wl/Wr/Wp into
// MFMA B-fragment order (lane-contiguous 16B so K-loop loads are coalesced).
// B-frag layout for 16x16x32: n = c*16 + (lane&15), k = kc*32 + (lane>>4)*8+j.
// ---------------------------------------------------------------------------
#define PREP_XC 3125                 // 50000*64/4 float4s / 256
#define PREP_PE (PREP_XC + 1280)     // 1024*1280/4 / 256
#define PREP_GC (PREP_PE + 196)
#define PREP_PL (PREP_GC + 8)        // 16 coltiles * 2 kc * 64 lanes / 256
#define PREP_PR (PREP_PL + 8)
#define PREP_PP (PREP_PR + 160)      // 16 * 40 * 64 / 256

__device__ inline void pack_frag(const float* __restrict__ src, bf16* __restrict__ dst,
                                 int KC, int tid) {
  int lane = tid & 63;
  int chunk = tid >> 6;            // = c*KC + kc
  int c = chunk / KC, kc = chunk - c * KC;
  int kbase = kc * 32 + ((lane >> 4) * 8);
  int n = c * 16 + (lane & 15);
#pragma unroll
  for (int j = 0; j < 8; ++j)
    dst[(size_t)tid * 8 + j] = __float2bfloat16(src[(size_t)(kbase + j) * HID + n]);
}

__global__ __launch_bounds__(256) void k_prep(
    const float* __restrict__ x, const float* __restrict__ pe,
    const float* __restrict__ Wl, const float* __restrict__ Wr,
    const float* __restrict__ Wp, const int* __restrict__ batch,
    bf16* __restrict__ xbf, bf16* __restrict__ pebf,
    bf16* __restrict__ Wl_pk, bf16* __restrict__ Wr_pk, bf16* __restrict__ Wp_pk,
    int* __restrict__ gcnt_i) {
  int b = blockIdx.x;
  if (b < PREP_XC) {
    int tid = b * 256 + threadIdx.x;
    float4 v = ((const float4*)x)[tid];
    bf16* d = xbf + (size_t)tid * 4;
    d[0] = __float2bfloat16(v.x); d[1] = __float2bfloat16(v.y);
    d[2] = __float2bfloat16(v.z); d[3] = __float2bfloat16(v.w);
  } else if (b < PREP_PE) {
    int tid = (b - PREP_XC) * 256 + threadIdx.x;
    float4 v = ((const float4*)pe)[tid];
    bf16* d = pebf + (size_t)tid * 4;
    d[0] = __float2bfloat16(v.x); d[1] = __float2bfloat16(v.y);
    d[2] = __float2bfloat16(v.z); d[3] = __float2bfloat16(v.w);
  } else if (b < PREP_GC) {
    int n = (b - PREP_PE) * 256 + threadIdx.x;
    if (n < N_NODES) atomicAdd(&gcnt_i[batch[n]], 1);
  } else if (b < PREP_PL) {
    pack_frag(Wl, Wl_pk, 2, (b - PREP_GC) * 256 + threadIdx.x);
  } else if (b < PREP_PR) {
    pack_frag(Wr, Wr_pk, 2, (b - PREP_PL) * 256 + threadIdx.x);
  } else {
    pack_frag(Wp, Wp_pk, 40, (b - PREP_PR) * 256 + threadIdx.x);
  }
}

// ---------------------------------------------------------------------------
// CSR build: histogram -> two-level scan -> fill
// ---------------------------------------------------------------------------
__global__ __launch_bounds__(256) void k_hist(const int* __restrict__ ei,
                                              int* __restrict__ degi) {
  int e = blockIdx.x * 256 + threadIdx.x;
  if (e < N_EDGES) atomicAdd(&degi[ei[N_EDGES + e]], 1);
}

__global__ __launch_bounds__(1024) void k_scan1(const int* __restrict__ degi,
                                                int* __restrict__ rowptr,
                                                int* __restrict__ totals) {
  __shared__ int wsum[16];
  const int t = threadIdx.x, lane = t & 63, wave = t >> 6;
  int i = blockIdx.x * 1024 + t;
  int v = (i < N_NODES) ? degi[i] : 0;
  int sc = v;
#pragma unroll
  for (int off = 1; off < 64; off <<= 1) {
    int u = __shfl_up(sc, off);
    if (lane >= off) sc += u;
  }
  if (lane == 63) wsum[wave] = sc;
  __syncthreads();
  if (t == 0) {
    int run = 0;
    for (int ww = 0; ww < 16; ++ww) { int vv = wsum[ww]; wsum[ww] = run; run += vv; }
    totals[blockIdx.x] = run;
    if (blockIdx.x == 0) rowptr[0] = 0;
  }
  __syncthreads();
  if (i < N_NODES) rowptr[i + 1] = wsum[wave] + sc;
}

__global__ __launch_bounds__(1024) void k_scan2(int* __restrict__ rowptr,
                                                const int* __restrict__ totals) {
  __shared__ int s_off;
  if (threadIdx.x == 0) {
    int o = 0;
    for (int j = 0; j < (int)blockIdx.x; ++j) o += totals[j];
    s_off = o;
  }
  __syncthreads();
  int i = blockIdx.x * 1024 + threadIdx.x;
  if (blockIdx.x > 0 && i < N_NODES) rowptr[i + 1] += s_off;
}

__global__ __launch_bounds__(256) void k_fill(const int* __restrict__ ei,
                                              const int* __restrict__ rowptr,
                                              int* __restrict__ cursor,
                                              int* __restrict__ esrc) {
  int e = blockIdx.x * 256 + threadIdx.x;
  if (e >= N_EDGES) return;
  int dst = ei[N_EDGES + e];
  int pos = atomicAdd(&cursor[dst], 1);
  esrc[rowptr[dst] + pos] = ei[e];
}

// ---------------------------------------------------------------------------
// k_gather: one wave per node, lane f = feature f, 8-deep load ILP, no LDS.
// Reads bf16 x (halves gather bytes), accumulates fp32, writes bf16 mean.
// ---------------------------------------------------------------------------
__global__ __launch_bounds__(256) void k_gather(
    const bf16* __restrict__ xbf, const int* __restrict__ rowptr,
    const int* __restrict__ esrc, bf16* __restrict__ aggrbf) {
  const int node = blockIdx.x * 4 + (threadIdx.x >> 6);
  const int f = threadIdx.x & 63;
  if (node >= N_NODES) return;
  const int beg = rowptr[node], end = rowptr[node + 1];
  float a0 = 0, a1 = 0, a2 = 0, a3 = 0, a4 = 0, a5 = 0, a6 = 0, a7 = 0;
  int e = beg;
  for (; e + 8 <= end; e += 8) {
    int s0 = esrc[e + 0], s1 = esrc[e + 1], s2 = esrc[e + 2], s3 = esrc[e + 3];
    int s4 = esrc[e + 4], s5 = esrc[e + 5], s6 = esrc[e + 6], s7 = esrc[e + 7];
    a0 += __bfloat162float(xbf[(size_t)s0 * D_IN + f]);
    a1 += __bfloat162float(xbf[(size_t)s1 * D_IN + f]);
    a2 += __bfloat162float(xbf[(size_t)s2 * D_IN + f]);
    a3 += __bfloat162float(xbf[(size_t)s3 * D_IN + f]);
    a4 += __bfloat162float(xbf[(size_t)s4 * D_IN + f]);
    a5 += __bfloat162float(xbf[(size_t)s5 * D_IN + f]);
    a6 += __bfloat162float(xbf[(size_t)s6 * D_IN + f]);
    a7 += __bfloat162float(xbf[(size_t)s7 * D_IN + f]);
  }
  for (; e < end; ++e) a0 += __bfloat162float(xbf[(size_t)esrc[e] * D_IN + f]);
  float sum = ((a0 + a1) + (a2 + a3)) + ((a4 + a5) + (a6 + a7));
  float inv = 1.0f / (float)max(end - beg, 1);
  aggrbf[(size_t)node * D_IN + f] = __float2bfloat16(sum * inv);
}

// ---------------------------------------------------------------------------
// k_mlp: MFMA GEMM [64 nodes x 128] @ [128 x 256] + bias + relu + mean-pool.
// C = aggrbf@Wl + xbf@Wr as two K=64 passes into the same accumulators.
// Wave w owns cols [64w,64w+64). No LDS in K-loop. Pool staged in LDS
// (sorted batch -> few graphs/block), flushed with ~ngl*256 global atomics.
// A-frag: lane reads A[(m0+lane&15)*64 + kc*32 + (lane>>4)*8 ..+7] (16B).
// ---------------------------------------------------------------------------
__global__ __launch_bounds__(256, 2) void k_mlp(
    const bf16* __restrict__ aggrbf, const bf16* __restrict__ xbf,
    const bf16* __restrict__ Wl_pk, const bf16* __restrict__ Wr_pk,
    const float* __restrict__ bl, const int* __restrict__ batch,
    float* __restrict__ pooled) {
  __shared__ float s_pool[16 * HID];  // 16 KB
  __shared__ int sG[64];
  const int t = threadIdx.x, w = t >> 6, lane = t & 63;
  const int ml = lane & 15, q = lane >> 4;
  const int n0 = blockIdx.x * 64;
  const int nn = min(64, N_NODES - n0);

  if (t < 64) sG[t] = (n0 + t < N_NODES) ? batch[n0 + t] : 0;
  for (int i = t; i < 16 * HID; i += 256) s_pool[i] = 0.f;

  f32x4 acc[4][4];
#pragma unroll
  for (int a = 0; a < 4; ++a)
#pragma unroll
    for (int c = 0; c < 4; ++c) acc[a][c] = (f32x4){0.f, 0.f, 0.f, 0.f};

#pragma unroll
  for (int mat = 0; mat < 2; ++mat) {
    const bf16* A = mat ? xbf : aggrbf;
    const bf16* B = mat ? Wr_pk : Wl_pk;
#pragma unroll
    for (int kc = 0; kc < 2; ++kc) {
      short8 af[4], bfr[4];
#pragma unroll
      for (int rt = 0; rt < 4; ++rt)
        af[rt] = *(const short8*)(A + (size_t)(n0 + rt * 16 + ml) * D_IN + kc * 32 + q * 8);
#pragma unroll
      for (int cl = 0; cl < 4; ++cl)
        bfr[cl] = *(const short8*)(B + ((size_t)((w * 4 + cl) * 2 + kc) * 64 + lane) * 8);
#pragma unroll
      for (int rt = 0; rt < 4; ++rt)
#pragma unroll
        for (int cl = 0; cl < 4; ++cl)
          acc[rt][cl] = __builtin_amdgcn_mfma_f32_16x16x32_bf16(af[rt], bfr[cl], acc[rt][cl], 0, 0, 0);
    }
  }

  __syncthreads();  // sG + s_pool ready
  const int g0 = sG[0];
  const int ngl = min(sG[nn - 1] - g0 + 1, 16);

#pragma unroll
  for (int cl = 0; cl < 4; ++cl) {
    const int col = w * 64 + cl * 16 + ml;
    const float bias = bl[col];
#pragma unroll
    for (int rt = 0; rt < 4; ++rt) {
      const int rbase = rt * 16 + q * 4;
      float run = 0.f; int rg = -1;
#pragma unroll
      for (int i = 0; i < 4; ++i) {
        int row = rbase + i;
        if (row >= nn) break;
        int g = sG[row];
        float v = fmaxf(acc[rt][cl][i] + bias, 0.f);
        if (g != rg) {
          if (rg >= 0) {
            int gl = rg - g0;
            if (gl < 16) atomicAdd(&s_pool[gl * HID + col], run);
            else atomicAdd(&pooled[(size_t)rg * HID + col], run);
          }
          rg = g; run = v;
        } else run += v;
      }
      if (rg >= 0) {
        int gl = rg - g0;
        if (gl < 16) atomicAdd(&s_pool[gl * HID + col], run);
        else atomicAdd(&pooled[(size_t)rg * HID + col], run);
      }
    }
  }
  __syncthreads();
  for (int idx = t; idx < ngl * HID; idx += 256) {
    float v = s_pool[idx];
    if (v != 0.f) atomicAdd(&pooled[(size_t)(g0 + (idx >> 8)) * HID + (idx & 255)], v);
  }
}

// ---------------------------------------------------------------------------
// k_prot: MFMA GEMM pe[1024x1280] @ Wp[1280x256] + bp -> prot (fp32).
// M-tile 16 (one row-tile), wave w owns 64 cols, 64 blocks.
// ---------------------------------------------------------------------------
__global__ __launch_bounds__(256) void k_prot(
    const bf16* __restrict__ pebf, const bf16* __restrict__ Wp_pk,
    const float* __restrict__ bp, float* __restrict__ prot) {
  const int w = threadIdx.x >> 6, lane = threadIdx.x & 63;
  const int ml = lane & 15, q = lane >> 4;
  const int g0 = blockIdx.x * 16;
  f32x4 acc[4];
#pragma unroll
  for (int c = 0; c < 4; ++c) acc[c] = (f32x4){0.f, 0.f, 0.f, 0.f};
  for (int kc = 0; kc < 40; ++kc) {
    short8 a = *(const short8*)(pebf + (size_t)(g0 + ml) * D_PROT + kc * 32 + q * 8);
#pragma unroll
    for (int cl = 0; cl < 4; ++cl) {
      short8 b = *(const short8*)(Wp_pk + ((size_t)((w * 4 + cl) * 40 + kc) * 64 + lane) * 8);
      acc[cl] = __builtin_amdgcn_mfma_f32_16x16x32_bf16(a, b, acc[cl], 0, 0, 0);
    }
  }
#pragma unroll
  for (int cl = 0; cl < 4; ++cl) {
    const int col = w * 64 + cl * 16 + ml;
    const float bias = bp[col];
#pragma unroll
    for (int i = 0; i < 4; ++i)
      prot[(size_t)(g0 + q * 4 + i) * HID + col] = acc[cl][i] + bias;
  }
}

// ---------------------------------------------------------------------------
// k_tail: per-graph interaction + head (fp32, small).
// ---------------------------------------------------------------------------
__global__ __launch_bounds__(256) void k_tail(
    const float* __restrict__ pooled, const int* __restrict__ gcnt_i,
    const float* __restrict__ prot,
    const float* __restrict__ Wi, const float* __restrict__ bi,
    const float* __restrict__ Wo, const float* __restrict__ bo,
    float* __restrict__ out) {
  __shared__ float sComb[GPB * 2 * HID];
  __shared__ float sRed[256];
  const int t = threadIdx.x;
  const int g0 = blockIdx.x * GPB;

  for (int g = 0; g < GPB; ++g) {
    float inv = 1.0f / fmaxf((float)gcnt_i[g0 + g], 1.0f);
    sComb[g * 2 * HID + t]       = pooled[(size_t)(g0 + g) * HID + t] * inv;
    sComb[g * 2 * HID + HID + t] = prot[(size_t)(g0 + g) * HID + t];
  }
  __syncthreads();

  float acci[GPB];
  const float bit = bi[t];
#pragma unroll
  for (int g = 0; g < GPB; ++g) acci[g] = bit;
  for (int j = 0; j < 2 * HID; ++j) {
    float wv = Wi[j * HID + t];
#pragma unroll
    for (int g = 0; g < GPB; ++g) acci[g] = fmaf(sComb[g * 2 * HID + j], wv, acci[g]);
  }

  const float wo = Wo[t];
  for (int g = 0; g < GPB; ++g) {
    float p = fmaxf(acci[g], 0.f) * wo;
    sRed[t] = p;
    __syncthreads();
    for (int s2 = 128; s2 > 0; s2 >>= 1) {
      if (t < s2) sRed[t] += sRed[t + s2];
      __syncthreads();
    }
    if (t == 0) out[g0 + g] = sRed[0] + bo[0];
    __syncthreads();
  }
}

extern "C" void kernel_launch(void* const* d_in, const int* in_sizes, int n_in,
                              void* d_out, int out_size, void* d_ws, size_t ws_size,
                              hipStream_t stream) {
  const float* x     = (const float*)d_in[0];
  const float* pe    = (const float*)d_in[1];
  const float* Wl    = (const float*)d_in[2];
  const float* bl    = (const float*)d_in[3];
  const float* Wr    = (const float*)d_in[4];
  const float* Wp    = (const float*)d_in[5];
  const float* bp    = (const float*)d_in[6];
  const float* Wi    = (const float*)d_in[7];
  const float* bi    = (const float*)d_in[8];
  const float* Wo    = (const float*)d_in[9];
  const float* bo    = (const float*)d_in[10];
  const int*   ei    = (const int*)d_in[11];
  const int*   batch = (const int*)d_in[12];
  float* out = (float*)d_out;

  // workspace layout, 256B-aligned chunks; zeroed region first
  char* p = (char*)d_ws;
  auto alloc = [&](size_t bytes) {
    char* r = p;
    p += (bytes + 255) & ~(size_t)255;
    return r;
  };
  int*   degi   = (int*)alloc(N_NODES * 4);
  int*   cursor = (int*)alloc(N_NODES * 4);
  int*   gcnt_i = (int*)alloc(N_GRAPHS * 4);
  float* pooled = (float*)alloc((size_t)N_GRAPHS * HID * 4);
  size_t zbytes = (size_t)(p - (char*)d_ws);
  int*   rowptr = (int*)alloc((N_NODES + 1) * 4);
  int*   totals = (int*)alloc(64 * 4);
  int*   esrc   = (int*)alloc((size_t)N_EDGES * 4);
  bf16*  xbf    = (bf16*)alloc((size_t)N_PAD * D_IN * 2);
  bf16*  aggrbf = (bf16*)alloc((size_t)N_PAD * D_IN * 2);
  bf16*  pebf   = (bf16*)alloc((size_t)N_GRAPHS * D_PROT * 2);
  bf16*  Wl_pk  = (bf16*)alloc(16384 * 2);
  bf16*  Wr_pk  = (bf16*)alloc(16384 * 2);
  bf16*  Wp_pk  = (bf16*)alloc(327680 * 2);
  float* prot   = (float*)alloc((size_t)N_GRAPHS * HID * 4);

  hipMemsetAsync(d_ws, 0, zbytes, stream);

  k_prep<<<PREP_PP, 256, 0, stream>>>(x, pe, Wl, Wr, Wp, batch,
                                      xbf, pebf, Wl_pk, Wr_pk, Wp_pk, gcnt_i);
  k_hist<<<(N_EDGES + 255) / 256, 256, 0, stream>>>(ei, degi);
  k_scan1<<<49, 1024, 0, stream>>>(degi, rowptr, totals);
  k_scan2<<<49, 1024, 0, stream>>>(rowptr, totals);
  k_fill<<<(N_EDGES + 255) / 256, 256, 0, stream>>>(ei, rowptr, cursor, esrc);
  k_gather<<<(N_NODES + 3) / 4, 256, 0, stream>>>(xbf, rowptr, esrc, aggrbf);
  k_prot<<<N_GRAPHS / 16, 256, 0, stream>>>(pebf, Wp_pk, bp, prot);
  k_mlp<<<(N_NODES + 63) / 64, 256, 0, stream>>>(aggrbf, xbf, Wl_pk, Wr_pk,
                                                 bl, batch, pooled);
  k_tail<<<N_GRAPHS / GPB, 256, 0, stream>>>(pooled, gcnt_i, prot,
                                             Wi, bi, Wo, bo, out);
}

// Round 4
// 255.875 us; speedup vs baseline: 3.7997x; 1.2748x over previous
//
#include <hip/hip_runtime.h>
#include <hip/hip_bf16.h>

#define N_NODES 50000
#define N_EDGES 800000
#define N_GRAPHS 1024
#define D_IN 64
#define D_PROT 1280
#define HID 256
#define GPB 4
#define N_PAD 50048  // N_NODES padded to multiple of 64

typedef __attribute__((ext_vector_type(8))) short short8;
typedef __attribute__((ext_vector_type(4))) float f32x4;
typedef __hip_bfloat16 bf16;

// round-to-nearest-even f32 -> bf16 bits (finite inputs only)
__device__ inline unsigned bf16rne(float f) {
  unsigned u = __float_as_uint(f);
  return (u + 0x7fffu + ((u >> 16) & 1u)) >> 16;
}
// accumulate 4 bf16 packed in uint2 into float4
__device__ inline void acc_bf2(float4& a, uint2 v) {
  a.x += __uint_as_float(v.x << 16);
  a.y += __uint_as_float(v.x & 0xffff0000u);
  a.z += __uint_as_float(v.y << 16);
  a.w += __uint_as_float(v.y & 0xffff0000u);
}

// ---------------------------------------------------------------------------
// k_prep: fused conversions + weight packing + in-degree histogram.
// Regions by blockIdx: x->bf16(uint2), pe->bf16(uint2), degi histogram,
// pack Wl/Wr/Wp into MFMA B-fragment order.
// ---------------------------------------------------------------------------
#define PREP_XC 3125                  // 50000*64/4 float4s / 256
#define PREP_PE (PREP_XC + 1280)      // 1024*1280/4 / 256
#define PREP_HI (PREP_PE + 3125)      // 800000 / 256
#define PREP_PL (PREP_HI + 8)         // 16 coltiles * 2 kc * 64 lanes / 256
#define PREP_PR (PREP_PL + 8)
#define PREP_PP (PREP_PR + 160)       // 16 * 40 * 64 / 256

__device__ inline void pack_frag(const float* __restrict__ src, bf16* __restrict__ dst,
                                 int KC, int tid) {
  int lane = tid & 63;
  int chunk = tid >> 6;            // = c*KC + kc
  int c = chunk / KC, kc = chunk - c * KC;
  int kbase = kc * 32 + ((lane >> 4) * 8);
  int n = c * 16 + (lane & 15);
#pragma unroll
  for (int j = 0; j < 8; ++j)
    dst[(size_t)tid * 8 + j] = __float2bfloat16(src[(size_t)(kbase + j) * HID + n]);
}

__global__ __launch_bounds__(256) void k_prep(
    const float* __restrict__ x, const float* __restrict__ pe,
    const float* __restrict__ Wl, const float* __restrict__ Wr,
    const float* __restrict__ Wp, const int* __restrict__ ei,
    uint2* __restrict__ x2, uint2* __restrict__ pe2,
    bf16* __restrict__ Wl_pk, bf16* __restrict__ Wr_pk, bf16* __restrict__ Wp_pk,
    int* __restrict__ degi) {
  int b = blockIdx.x;
  if (b < PREP_XC) {
    int tid = b * 256 + threadIdx.x;
    float4 v = ((const float4*)x)[tid];
    x2[tid] = make_uint2(bf16rne(v.x) | (bf16rne(v.y) << 16),
                         bf16rne(v.z) | (bf16rne(v.w) << 16));
  } else if (b < PREP_PE) {
    int tid = (b - PREP_XC) * 256 + threadIdx.x;
    float4 v = ((const float4*)pe)[tid];
    pe2[tid] = make_uint2(bf16rne(v.x) | (bf16rne(v.y) << 16),
                          bf16rne(v.z) | (bf16rne(v.w) << 16));
  } else if (b < PREP_HI) {
    int e = (b - PREP_PE) * 256 + threadIdx.x;
    if (e < N_EDGES) atomicAdd(&degi[ei[N_EDGES + e]], 1);
  } else if (b < PREP_PL) {
    pack_frag(Wl, Wl_pk, 2, (b - PREP_HI) * 256 + threadIdx.x);
  } else if (b < PREP_PR) {
    pack_frag(Wr, Wr_pk, 2, (b - PREP_PL) * 256 + threadIdx.x);
  } else {
    pack_frag(Wp, Wp_pk, 40, (b - PREP_PR) * 256 + threadIdx.x);
  }
}

// ---------------------------------------------------------------------------
// CSR build: two-level scan + fill
// ---------------------------------------------------------------------------
__global__ __launch_bounds__(1024) void k_scan1(const int* __restrict__ degi,
                                                int* __restrict__ rowptr,
                                                int* __restrict__ totals) {
  __shared__ int wsum[16];
  const int t = threadIdx.x, lane = t & 63, wave = t >> 6;
  int i = blockIdx.x * 1024 + t;
  int v = (i < N_NODES) ? degi[i] : 0;
  int sc = v;
#pragma unroll
  for (int off = 1; off < 64; off <<= 1) {
    int u = __shfl_up(sc, off);
    if (lane >= off) sc += u;
  }
  if (lane == 63) wsum[wave] = sc;
  __syncthreads();
  if (t == 0) {
    int run = 0;
    for (int ww = 0; ww < 16; ++ww) { int vv = wsum[ww]; wsum[ww] = run; run += vv; }
    totals[blockIdx.x] = run;
    if (blockIdx.x == 0) rowptr[0] = 0;
  }
  __syncthreads();
  if (i < N_NODES) rowptr[i + 1] = wsum[wave] + sc;
}

__global__ __launch_bounds__(1024) void k_scan2(int* __restrict__ rowptr,
                                                const int* __restrict__ totals) {
  __shared__ int s_off;
  if (threadIdx.x == 0) {
    int o = 0;
    for (int j = 0; j < (int)blockIdx.x; ++j) o += totals[j];
    s_off = o;
  }
  __syncthreads();
  int i = blockIdx.x * 1024 + threadIdx.x;
  if (blockIdx.x > 0 && i < N_NODES) rowptr[i + 1] += s_off;
}

__global__ __launch_bounds__(256) void k_fill(const int* __restrict__ ei,
                                              const int* __restrict__ rowptr,
                                              int* __restrict__ cursor,
                                              int* __restrict__ esrc) {
  int e = blockIdx.x * 256 + threadIdx.x;
  if (e >= N_EDGES) return;
  int dst = ei[N_EDGES + e];
  int pos = atomicAdd(&cursor[dst], 1);
  esrc[rowptr[dst] + pos] = ei[e];
}

// ---------------------------------------------------------------------------
// k_gather: one wave per node. Lane layout: slot el=lane>>4 (edge), fb=lane&15
// (uint2 = 4 features). 4 edges per step x 4-deep ILP = 16 edges in flight
// (avg degree 16). Butterfly shuffle-reduce across the 4 slots; lanes 0..15
// write the mean row as uint2 (128 B per wave).
// ---------------------------------------------------------------------------
__global__ __launch_bounds__(256) void k_gather(
    const uint2* __restrict__ x2, const int* __restrict__ rowptr,
    const int* __restrict__ esrc, uint2* __restrict__ a2) {
  const int node = blockIdx.x * 4 + (threadIdx.x >> 6);
  const int lane = threadIdx.x & 63;
  const int el = lane >> 4;
  const int fb = lane & 15;
  if (node >= N_NODES) return;
  const int beg = rowptr[node], end = rowptr[node + 1];
  float4 s0 = {0,0,0,0}, s1 = {0,0,0,0}, s2 = {0,0,0,0}, s3 = {0,0,0,0};
  int e = beg;
  for (; e + 16 <= end; e += 16) {
    int i0 = esrc[e + el], i1 = esrc[e + 4 + el];
    int i2 = esrc[e + 8 + el], i3 = esrc[e + 12 + el];
    uint2 v0 = x2[(size_t)i0 * 16 + fb];
    uint2 v1 = x2[(size_t)i1 * 16 + fb];
    uint2 v2 = x2[(size_t)i2 * 16 + fb];
    uint2 v3 = x2[(size_t)i3 * 16 + fb];
    acc_bf2(s0, v0); acc_bf2(s1, v1); acc_bf2(s2, v2); acc_bf2(s3, v3);
  }
  for (; e + 4 <= end; e += 4) {
    int i0 = esrc[e + el];
    acc_bf2(s0, x2[(size_t)i0 * 16 + fb]);
  }
  if (e + el < end) {
    int i0 = esrc[e + el];
    acc_bf2(s1, x2[(size_t)i0 * 16 + fb]);
  }
  float4 tt;
  tt.x = (s0.x + s1.x) + (s2.x + s3.x);
  tt.y = (s0.y + s1.y) + (s2.y + s3.y);
  tt.z = (s0.z + s1.z) + (s2.z + s3.z);
  tt.w = (s0.w + s1.w) + (s2.w + s3.w);
  tt.x += __shfl_xor(tt.x, 32); tt.x += __shfl_xor(tt.x, 16);
  tt.y += __shfl_xor(tt.y, 32); tt.y += __shfl_xor(tt.y, 16);
  tt.z += __shfl_xor(tt.z, 32); tt.z += __shfl_xor(tt.z, 16);
  tt.w += __shfl_xor(tt.w, 32); tt.w += __shfl_xor(tt.w, 16);
  if (el == 0) {
    float inv = 1.0f / (float)max(end - beg, 1);
    uint2 o;
    o.x = bf16rne(tt.x * inv) | (bf16rne(tt.y * inv) << 16);
    o.y = bf16rne(tt.z * inv) | (bf16rne(tt.w * inv) << 16);
    a2[(size_t)node * 16 + fb] = o;
  }
}

// ---------------------------------------------------------------------------
// k_mlp: pure MFMA GEMM [64 rows x 128] @ [128 x 256] + bias + relu ->
// drug (bf16). No LDS, no atomics, no divergent branches.
// ---------------------------------------------------------------------------
__global__ __launch_bounds__(256) void k_mlp(
    const bf16* __restrict__ aggrbf, const bf16* __restrict__ xbf,
    const bf16* __restrict__ Wl_pk, const bf16* __restrict__ Wr_pk,
    const float* __restrict__ bl, unsigned short* __restrict__ drug) {
  const int t = threadIdx.x, w = t >> 6, lane = t & 63;
  const int ml = lane & 15, q = lane >> 4;
  const int n0 = blockIdx.x * 64;

  f32x4 acc[4][4];
#pragma unroll
  for (int a = 0; a < 4; ++a)
#pragma unroll
    for (int c = 0; c < 4; ++c) acc[a][c] = (f32x4){0.f, 0.f, 0.f, 0.f};

#pragma unroll
  for (int mat = 0; mat < 2; ++mat) {
    const bf16* A = mat ? xbf : aggrbf;
    const bf16* B = mat ? Wr_pk : Wl_pk;
#pragma unroll
    for (int kc = 0; kc < 2; ++kc) {
      short8 af[4], bfr[4];
#pragma unroll
      for (int rt = 0; rt < 4; ++rt)
        af[rt] = *(const short8*)(A + (size_t)(n0 + rt * 16 + ml) * D_IN + kc * 32 + q * 8);
#pragma unroll
      for (int cl = 0; cl < 4; ++cl)
        bfr[cl] = *(const short8*)(B + ((size_t)((w * 4 + cl) * 2 + kc) * 64 + lane) * 8);
#pragma unroll
      for (int rt = 0; rt < 4; ++rt)
#pragma unroll
        for (int cl = 0; cl < 4; ++cl)
          acc[rt][cl] = __builtin_amdgcn_mfma_f32_16x16x32_bf16(af[rt], bfr[cl], acc[rt][cl], 0, 0, 0);
    }
  }

#pragma unroll
  for (int cl = 0; cl < 4; ++cl) {
    const int col = w * 64 + cl * 16 + ml;
    const float bias = bl[col];
#pragma unroll
    for (int rt = 0; rt < 4; ++rt) {
#pragma unroll
      for (int i = 0; i < 4; ++i) {
        const int row = n0 + rt * 16 + q * 4 + i;
        drug[(size_t)row * HID + col] =
            (unsigned short)bf16rne(fmaxf(acc[rt][cl][i] + bias, 0.f));
      }
    }
  }
}

// ---------------------------------------------------------------------------
// k_pool: one block per graph; binary search sorted batch for row range,
// column-sum drug rows (coalesced 512B/row), write mean. Zero atomics.
// ---------------------------------------------------------------------------
__device__ inline int lb_dev(const int* __restrict__ a, int v) {
  int lo = 0, hi = N_NODES;
  while (lo < hi) { int m = (lo + hi) >> 1; if (a[m] < v) lo = m + 1; else hi = m; }
  return lo;
}

__global__ __launch_bounds__(256) void k_pool(
    const unsigned short* __restrict__ drug, const int* __restrict__ batch,
    float* __restrict__ pooled) {
  const int g = blockIdx.x, t = threadIdx.x;
  const int lo = lb_dev(batch, g);
  const int hi = lb_dev(batch, g + 1);
  float s0 = 0.f, s1 = 0.f, s2 = 0.f, s3 = 0.f;
  int r = lo;
  for (; r + 4 <= hi; r += 4) {
    s0 += __uint_as_float((unsigned)drug[(size_t)(r + 0) * HID + t] << 16);
    s1 += __uint_as_float((unsigned)drug[(size_t)(r + 1) * HID + t] << 16);
    s2 += __uint_as_float((unsigned)drug[(size_t)(r + 2) * HID + t] << 16);
    s3 += __uint_as_float((unsigned)drug[(size_t)(r + 3) * HID + t] << 16);
  }
  for (; r < hi; ++r)
    s0 += __uint_as_float((unsigned)drug[(size_t)r * HID + t] << 16);
  float inv = 1.0f / (float)max(hi - lo, 1);
  pooled[(size_t)g * HID + t] = ((s0 + s1) + (s2 + s3)) * inv;
}

// ---------------------------------------------------------------------------
// k_prot: pe[1024x1280] @ Wp[1280x256], K-split x4 -> prot4 partial slices.
// 256 blocks = 64 M-tiles x 4 K-chunks; wave w owns 64 cols.
// ---------------------------------------------------------------------------
__global__ __launch_bounds__(256) void k_prot(
    const bf16* __restrict__ pebf, const bf16* __restrict__ Wp_pk,
    float* __restrict__ prot4) {
  const int w = threadIdx.x >> 6, lane = threadIdx.x & 63;
  const int ml = lane & 15, q = lane >> 4;
  const int mt = blockIdx.x >> 2, ks = blockIdx.x & 3;
  const int g0 = mt * 16, kc0 = ks * 10;
  f32x4 acc[4];
#pragma unroll
  for (int c = 0; c < 4; ++c) acc[c] = (f32x4){0.f, 0.f, 0.f, 0.f};
  for (int kc = kc0; kc < kc0 + 10; ++kc) {
    short8 a = *(const short8*)(pebf + (size_t)(g0 + ml) * D_PROT + kc * 32 + q * 8);
#pragma unroll
    for (int cl = 0; cl < 4; ++cl) {
      short8 b = *(const short8*)(Wp_pk + ((size_t)((w * 4 + cl) * 40 + kc) * 64 + lane) * 8);
      acc[cl] = __builtin_amdgcn_mfma_f32_16x16x32_bf16(a, b, acc[cl], 0, 0, 0);
    }
  }
#pragma unroll
  for (int cl = 0; cl < 4; ++cl) {
    const int col = w * 64 + cl * 16 + ml;
#pragma unroll
    for (int i = 0; i < 4; ++i)
      prot4[((size_t)ks * N_GRAPHS + g0 + q * 4 + i) * HID + col] = acc[cl][i];
  }
}

// ---------------------------------------------------------------------------
// k_tail: combined = [pooled | sum(prot4)+bp]; inter = relu(@Wi+bi);
// out = inter@Wo + bo. Wave-shuffle head reduction.
// ---------------------------------------------------------------------------
__global__ __launch_bounds__(256) void k_tail(
    const float* __restrict__ pooled, const float* __restrict__ prot4,
    const float* __restrict__ bp,
    const float* __restrict__ Wi, const float* __restrict__ bi,
    const float* __restrict__ Wo, const float* __restrict__ bo,
    float* __restrict__ out) {
  __shared__ float sComb[GPB * 2 * HID];
  __shared__ float sRed[4 * GPB];
  const int t = threadIdx.x, w = t >> 6, lane = t & 63;
  const int g0 = blockIdx.x * GPB;

  for (int g = 0; g < GPB; ++g) {
    size_t idx = (size_t)(g0 + g) * HID + t;
    sComb[g * 2 * HID + t] = pooled[idx];
    float pr = prot4[idx] + prot4[(size_t)N_GRAPHS * HID + idx]
             + prot4[2 * (size_t)N_GRAPHS * HID + idx]
             + prot4[3 * (size_t)N_GRAPHS * HID + idx];
    sComb[g * 2 * HID + HID + t] = pr + bp[t];
  }
  __syncthreads();

  float acci[GPB];
  const float bit = bi[t];
#pragma unroll
  for (int g = 0; g < GPB; ++g) acci[g] = bit;
  for (int j = 0; j < 2 * HID; ++j) {
    float wv = Wi[j * HID + t];
#pragma unroll
    for (int g = 0; g < GPB; ++g) acci[g] = fmaf(sComb[g * 2 * HID + j], wv, acci[g]);
  }

  const float wo = Wo[t];
  float p[GPB];
#pragma unroll
  for (int g = 0; g < GPB; ++g) p[g] = fmaxf(acci[g], 0.f) * wo;
#pragma unroll
  for (int off = 32; off > 0; off >>= 1)
#pragma unroll
    for (int g = 0; g < GPB; ++g) p[g] += __shfl_down(p[g], off);
  if (lane == 0)
    for (int g = 0; g < GPB; ++g) sRed[w * GPB + g] = p[g];
  __syncthreads();
  if (t < GPB)
    out[g0 + t] = sRed[0 * GPB + t] + sRed[1 * GPB + t] + sRed[2 * GPB + t]
                + sRed[3 * GPB + t] + bo[0];
}

extern "C" void kernel_launch(void* const* d_in, const int* in_sizes, int n_in,
                              void* d_out, int out_size, void* d_ws, size_t ws_size,
                              hipStream_t stream) {
  const float* x     = (const float*)d_in[0];
  const float* pe    = (const float*)d_in[1];
  const float* Wl    = (const float*)d_in[2];
  const float* bl    = (const float*)d_in[3];
  const float* Wr    = (const float*)d_in[4];
  const float* Wp    = (const float*)d_in[5];
  const float* bp    = (const float*)d_in[6];
  const float* Wi    = (const float*)d_in[7];
  const float* bi    = (const float*)d_in[8];
  const float* Wo    = (const float*)d_in[9];
  const float* bo    = (const float*)d_in[10];
  const int*   ei    = (const int*)d_in[11];
  const int*   batch = (const int*)d_in[12];
  float* out = (float*)d_out;

  char* p = (char*)d_ws;
  auto alloc = [&](size_t bytes) {
    char* r = p;
    p += (bytes + 255) & ~(size_t)255;
    return r;
  };
  int*   degi   = (int*)alloc(N_NODES * 4);
  int*   cursor = (int*)alloc(N_NODES * 4);
  size_t zbytes = (size_t)(p - (char*)d_ws);   // only degi+cursor need zeroing
  int*   rowptr = (int*)alloc((N_NODES + 1) * 4);
  int*   totals = (int*)alloc(64 * 4);
  int*   esrc   = (int*)alloc((size_t)N_EDGES * 4);
  bf16*  xbf    = (bf16*)alloc((size_t)N_PAD * D_IN * 2);
  bf16*  aggrbf = (bf16*)alloc((size_t)N_PAD * D_IN * 2);
  bf16*  pebf   = (bf16*)alloc((size_t)N_GRAPHS * D_PROT * 2);
  bf16*  Wl_pk  = (bf16*)alloc((size_t)D_IN * HID * 2);
  bf16*  Wr_pk  = (bf16*)alloc((size_t)D_IN * HID * 2);
  bf16*  Wp_pk  = (bf16*)alloc((size_t)D_PROT * HID * 2);
  float* prot4  = (float*)alloc((size_t)4 * N_GRAPHS * HID * 4);
  unsigned short* drug = (unsigned short*)alloc((size_t)N_PAD * HID * 2);
  float* pooled = (float*)alloc((size_t)N_GRAPHS * HID * 4);

  hipMemsetAsync(d_ws, 0, zbytes, stream);

  k_prep<<<PREP_PP, 256, 0, stream>>>(x, pe, Wl, Wr, Wp, ei,
                                      (uint2*)xbf, (uint2*)pebf,
                                      Wl_pk, Wr_pk, Wp_pk, degi);
  k_scan1<<<49, 1024, 0, stream>>>(degi, rowptr, totals);
  k_scan2<<<49, 1024, 0, stream>>>(rowptr, totals);
  k_fill<<<(N_EDGES + 255) / 256, 256, 0, stream>>>(ei, rowptr, cursor, esrc);
  k_gather<<<(N_NODES + 3) / 4, 256, 0, stream>>>((const uint2*)xbf, rowptr, esrc,
                                                  (uint2*)aggrbf);
  k_prot<<<256, 256, 0, stream>>>(pebf, Wp_pk, prot4);
  k_mlp<<<N_PAD / 64, 256, 0, stream>>>(aggrbf, xbf, Wl_pk, Wr_pk, bl, drug);
  k_pool<<<N_GRAPHS, 256, 0, stream>>>(drug, batch, pooled);
  k_tail<<<N_GRAPHS / GPB, 256, 0, stream>>>(pooled, prot4, bp,
                                             Wi, bi, Wo, bo, out);
}